// Round 5
// baseline (1645.569 us; speedup 1.0000x reference)
//
#include <hip/hip_runtime.h>
#include <hip/hip_bf16.h>

#define N_NODES 100000
#define N_EDGES 3200000
#define N_GRAPHS 1024
#define NCLS 21
#define TILE_N 32
#define K_BUCKETS 3125   // N_NODES / TILE_N exactly
#define NB 256           // streaming blocks for hist/bin
#define CHUNK 12500      // N_EDGES / NB

__device__ __forceinline__ float rlanef(float v, int l) {
    return __int_as_float(__builtin_amdgcn_readlane(__float_as_int(v), l));
}

// ---- bucket histogram: per-block LDS hist, flush with one atomic per bucket ----
__global__ __launch_bounds__(256) void k_hist(const int* __restrict__ dst,
                                              int* __restrict__ bh) {
    __shared__ int lh[K_BUCKETS];
    for (int i = threadIdx.x; i < K_BUCKETS; i += 256) lh[i] = 0;
    __syncthreads();
    int e0 = blockIdx.x * CHUNK;
    for (int e = e0 + threadIdx.x; e < e0 + CHUNK; e += 256)
        atomicAdd(&lh[dst[e] >> 5], 1);
    __syncthreads();
    for (int i = threadIdx.x; i < K_BUCKETS; i += 256)
        if (lh[i]) atomicAdd(&bh[i], lh[i]);
}

// ---- exclusive scan over 3125 bucket counts (single block), init cursors ----
__global__ __launch_bounds__(1024) void k_scan(int* __restrict__ bh,
                                               int* __restrict__ cursor) {
    __shared__ int lds[1024];
    int t = threadIdx.x;
    int base = t * 4;
    int v[4];
#pragma unroll
    for (int i = 0; i < 4; i++) v[i] = (base + i < K_BUCKETS) ? bh[base + i] : 0;
    int tsum = v[0] + v[1] + v[2] + v[3];
    lds[t] = tsum;
    __syncthreads();
    for (int off = 1; off < 1024; off <<= 1) {
        int cur = lds[t];
        int add = (t >= off) ? lds[t - off] : 0;
        __syncthreads();
        lds[t] = cur + add;
        __syncthreads();
    }
    int run = lds[t] - tsum;
#pragma unroll
    for (int i = 0; i < 4; i++) {
        if (base + i < K_BUCKETS) { bh[base + i] = run; cursor[base + i] = run; }
        run += v[i];
    }
}

// ---- bin edges by dst bucket via global cursor atomics ----
// payload: (src << 5) | (dst & 31);  bucket regions are dense 4KB runs -> good
// write locality (lines fill completely, unlike the 100k-bin R1 scatter)
__global__ __launch_bounds__(256) void k_bin(const int* __restrict__ src,
                                             const int* __restrict__ dst,
                                             int* __restrict__ cursor,
                                             unsigned int* __restrict__ bins) {
    int e0 = blockIdx.x * CHUNK;
    for (int e = e0 + threadIdx.x; e < e0 + CHUNK; e += 256) {
        int dd = dst[e];
        int pos = atomicAdd(&cursor[dd >> 5], 1);
        bins[pos] = ((unsigned int)src[e] << 5) | (unsigned int)(dd & 31);
    }
}

// ---- layer 1: bucket aggregate + count + linear + relu -> h1b (bf16), cnt, gcnt ----
__global__ __launch_bounds__(256) void k_l1agg(
    const int* __restrict__ S, const unsigned int* __restrict__ bins,
    const float* __restrict__ x,
    const float* __restrict__ W1l, const float* __restrict__ b1,
    const float* __restrict__ W1r,
    const int* __restrict__ batch, float* __restrict__ gcnt,
    __hip_bfloat16* __restrict__ h1b, int* __restrict__ cnt) {
    __shared__ float t1[TILE_N];
    __shared__ int   tc[TILE_N];
    int k = blockIdx.x;
    if (threadIdx.x < TILE_N) { t1[threadIdx.x] = 0.0f; tc[threadIdx.x] = 0; }
    __syncthreads();
    int e0 = S[k];
    int e1 = (k == K_BUCKETS - 1) ? N_EDGES : S[k + 1];
    for (int i = e0 + threadIdx.x; i < e1; i += 256) {
        unsigned int p = bins[i];
        atomicAdd(&t1[p & 31u], x[p >> 5]);
        atomicAdd(&tc[p & 31u], 1);
    }
    __syncthreads();
    if (threadIdx.x < TILE_N) {
        int n = k * TILE_N + threadIdx.x;          // 3125*32 == 100000 exactly
        cnt[n] = tc[threadIdx.x];
        atomicAdd(&gcnt[batch[n]], 1.0f);
    }
    for (int i = threadIdx.x; i < TILE_N * 64; i += 256) {
        int slot = i >> 6, f = i & 63;
        int n = k * TILE_N + slot;
        float a = t1[slot] / fmaxf((float)tc[slot], 1.0f);
        float v = a * W1l[f] + b1[f] + x[n] * W1r[f];
        h1b[(size_t)n * 64 + f] = __float2bfloat16(fmaxf(v, 0.0f));
    }
}

// ---- layer 2 gather phase: low-VGPR, 8KB LDS -> full occupancy ----
__global__ __launch_bounds__(256) void k_agg2(
    const int* __restrict__ S, const unsigned int* __restrict__ bins,
    const __hip_bfloat16* __restrict__ h1b, const int* __restrict__ cnt,
    __hip_bfloat16* __restrict__ agg2b) {
    __shared__ float tile[TILE_N * 64];   // 8 KB
    int k = blockIdx.x;
    int f = threadIdx.x & 63;
    int wid = threadIdx.x >> 6;
    for (int i = threadIdx.x; i < TILE_N * 64; i += 256) tile[i] = 0.0f;
    __syncthreads();

    int e0 = S[k];
    int e1 = (k == K_BUCKETS - 1) ? N_EDGES : S[k + 1];
    for (int g = e0 + wid * 64; g < e1; g += 256) {
        int idx = g + f;
        unsigned int p = (idx < e1) ? bins[idx] : 0u;
        int d = (int)(p & 31u);
        int s = (int)(p >> 5);
        int c = min(64, e1 - g);
        int j = 0;
        for (; j + 8 <= c; j += 8) {
            int dd[8]; float vv[8];
#pragma unroll
            for (int i = 0; i < 8; i++) {
                dd[i] = __builtin_amdgcn_readlane(d, j + i);
                int sj = __builtin_amdgcn_readlane(s, j + i);
                vv[i] = __bfloat162float(h1b[(size_t)sj * 64 + f]);  // 128B/edge
            }
#pragma unroll
            for (int i = 0; i < 8; i++) atomicAdd(&tile[dd[i] * 64 + f], vv[i]);
        }
        for (; j < c; ++j) {
            int dj = __builtin_amdgcn_readlane(d, j);
            int sj = __builtin_amdgcn_readlane(s, j);
            atomicAdd(&tile[dj * 64 + f], __bfloat162float(h1b[(size_t)sj * 64 + f]));
        }
    }
    __syncthreads();
    for (int i = threadIdx.x; i < TILE_N * 64; i += 256) {
        int slot = i >> 6, ff = i & 63;
        int n = k * TILE_N + slot;
        float m = tile[i] / fmaxf((float)cnt[n], 1.0f);
        agg2b[(size_t)n * 64 + ff] = __float2bfloat16(m);
    }
}

// ---- layer 2 GEMV phase: weights in LDS (no VGPR blowup / no scratch) ----
__global__ __launch_bounds__(256) void k_node2b(
    const __hip_bfloat16* __restrict__ agg2b, const __hip_bfloat16* __restrict__ h1b,
    const float* __restrict__ W2l, const float* __restrict__ b2,
    const float* __restrict__ W2r,
    const int* __restrict__ batch, const float* __restrict__ gcnt,
    float* __restrict__ pooled) {
    __shared__ float wl[64 * 64];   // 16 KB
    __shared__ float wr[64 * 64];   // 16 KB
    for (int i = threadIdx.x; i < 4096; i += 256) { wl[i] = W2l[i]; wr[i] = W2r[i]; }
    __syncthreads();
    int f = threadIdx.x & 63;
    int wid = threadIdx.x >> 6;
    float bias = b2[f];
    int n0 = blockIdx.x * 64;
    for (int t = wid; t < 64; t += 4) {
        int n = n0 + t;
        if (n >= N_NODES) break;
        float m = __bfloat162float(agg2b[(size_t)n * 64 + f]);
        float h = __bfloat162float(h1b[(size_t)n * 64 + f]);
        float acc = bias;
#pragma unroll
        for (int kk = 0; kk < 64; kk++) {
            acc += rlanef(m, kk) * wl[kk * 64 + f];   // lanes hit 64 consecutive
            acc += rlanef(h, kk) * wr[kk * 64 + f];   // floats: 2-way bank = free
        }
        acc = fmaxf(acc, 0.0f);
        int b = batch[n];
        atomicAdd(&pooled[b * 64 + f], acc / fmaxf(gcnt[b], 1.0f));
    }
}

// ---- classifier ----
__global__ void k_cls(const float* __restrict__ pooled, const float* __restrict__ Wc,
                      const float* __restrict__ bc, float* __restrict__ out) {
    __shared__ float rowv[64];
    int g = blockIdx.x;
    int f = threadIdx.x;
    rowv[f] = pooled[g * 64 + f];
    __syncthreads();
    if (f < NCLS) {
        float acc = bc[f];
#pragma unroll
        for (int kk = 0; kk < 64; kk++) acc += rowv[kk] * Wc[kk * NCLS + f];
        out[g * NCLS + f] = acc;
    }
}

extern "C" void kernel_launch(void* const* d_in, const int* in_sizes, int n_in,
                              void* d_out, int out_size, void* d_ws, size_t ws_size,
                              hipStream_t stream) {
    const float* x     = (const float*)d_in[0];
    const int*   eidx  = (const int*)d_in[1];
    const int*   batch = (const int*)d_in[2];
    const float* W1l   = (const float*)d_in[3];
    const float* b1    = (const float*)d_in[4];
    const float* W1r   = (const float*)d_in[5];
    const float* W2l   = (const float*)d_in[6];
    const float* b2    = (const float*)d_in[7];
    const float* W2r   = (const float*)d_in[8];
    const float* Wc    = (const float*)d_in[9];
    const float* bc    = (const float*)d_in[10];
    float* out = (float*)d_out;

    const int* src = eidx;
    const int* dst = eidx + N_EDGES;

    // workspace layout — ~39.1 MB total (proven-safe envelope is 40.27 MB)
    char* p = (char*)d_ws;
    unsigned int* bins  = (unsigned int*)p;   p += (size_t)N_EDGES * 4;        // 12.8 MB
    __hip_bfloat16* h1b = (__hip_bfloat16*)p; p += (size_t)N_NODES * 64 * 2;   // 12.8 MB
    __hip_bfloat16* agg2b = (__hip_bfloat16*)p; p += (size_t)N_NODES * 64 * 2; // 12.8 MB
    int*   cnt    = (int*)p;                  p += (size_t)N_NODES * 4;        // 0.4 MB
    int*   cursor = (int*)p;                  p += K_BUCKETS * 4;
    // ---- zeroed region (contiguous) ----
    int*   bh     = (int*)p;                  p += K_BUCKETS * 4;
    float* gcnt   = (float*)p;                p += N_GRAPHS * 4;
    float* pooled = (float*)p;                p += (size_t)N_GRAPHS * 64 * 4;
    size_t zero_bytes = (size_t)(K_BUCKETS + N_GRAPHS + N_GRAPHS * 64) * 4;

    hipMemsetAsync(bh, 0, zero_bytes, stream);

    k_hist  <<<NB, 256, 0, stream>>>(dst, bh);
    k_scan  <<<1, 1024, 0, stream>>>(bh, cursor);
    k_bin   <<<NB, 256, 0, stream>>>(src, dst, cursor, bins);

    k_l1agg <<<K_BUCKETS, 256, 0, stream>>>(bh, bins, x, W1l, b1, W1r, batch, gcnt, h1b, cnt);
    k_agg2  <<<K_BUCKETS, 256, 0, stream>>>(bh, bins, h1b, cnt, agg2b);
    k_node2b<<<(N_NODES + 63) / 64, 256, 0, stream>>>(agg2b, h1b, W2l, b2, W2r,
                                                      batch, gcnt, pooled);
    k_cls   <<<N_GRAPHS, 64, 0, stream>>>(pooled, Wc, bc, out);
}

// Round 6
// 1550.894 us; speedup vs baseline: 1.0610x; 1.0610x over previous
//
#include <hip/hip_runtime.h>

#define N_NODES 100000
#define N_EDGES 3200000
#define N_GRAPHS 1024
#define NCLS 21
#define TILE_N 32
#define K_BUCKETS 3125   // N_NODES / TILE_N exactly
#define BSTRIDE 2048     // bucket capacity: mean 1024, sigma 32 -> +32 sigma

__device__ __forceinline__ float rlanef(float v, int l) {
    return __int_as_float(__builtin_amdgcn_readlane(__float_as_int(v), l));
}
__device__ __forceinline__ float bf2f(unsigned short u) {
    return __uint_as_float(((unsigned)u) << 16);
}
__device__ __forceinline__ unsigned short f2bf(float f) {
    unsigned u = __float_as_uint(f);
    unsigned r = 0x7fffu + ((u >> 16) & 1u);   // RNE
    return (unsigned short)((u + r) >> 16);
}

// ---- single-pass bin: cursor atomics double as bucket counts ----
// payload: (src << 5) | (dst & 31)
__global__ __launch_bounds__(256) void k_bin2(const int* __restrict__ src,
                                              const int* __restrict__ dst,
                                              int* __restrict__ bh,
                                              unsigned int* __restrict__ bins) {
    int stride = gridDim.x * 256;
    for (int e = blockIdx.x * 256 + threadIdx.x; e < N_EDGES; e += stride) {
        int dd = dst[e];
        int b = dd >> 5;
        int slot = atomicAdd(&bh[b], 1);
        if (slot < BSTRIDE)
            bins[(size_t)b * BSTRIDE + slot] =
                ((unsigned)src[e] << 5) | (unsigned)(dd & 31);
    }
}

// ---- layer 1: bucket aggregate + count + linear + relu -> h1b, cnt, gcnt ----
__global__ __launch_bounds__(256) void k_l1agg(
    const int* __restrict__ bh, const unsigned int* __restrict__ bins,
    const float* __restrict__ x,
    const float* __restrict__ W1l, const float* __restrict__ b1,
    const float* __restrict__ W1r,
    const int* __restrict__ batch, float* __restrict__ gcnt,
    unsigned short* __restrict__ h1b, int* __restrict__ cnt) {
    __shared__ float t1[TILE_N];
    __shared__ int   tc[TILE_N];
    int k = blockIdx.x;
    if (threadIdx.x < TILE_N) { t1[threadIdx.x] = 0.0f; tc[threadIdx.x] = 0; }
    __syncthreads();
    int c = min(bh[k], BSTRIDE);
    const unsigned int* bb = bins + (size_t)k * BSTRIDE;
    for (int i = threadIdx.x; i < c; i += 256) {
        unsigned p = bb[i];
        atomicAdd(&t1[p & 31u], x[p >> 5]);
        atomicAdd(&tc[p & 31u], 1);
    }
    __syncthreads();
    if (threadIdx.x < TILE_N) {
        int n = k * TILE_N + threadIdx.x;   // 3125*32 == 100000 exactly
        cnt[n] = tc[threadIdx.x];
        atomicAdd(&gcnt[batch[n]], 1.0f);
    }
    for (int i = threadIdx.x; i < TILE_N * 64; i += 256) {
        int slot = i >> 6, f = i & 63;
        int n = k * TILE_N + slot;
        float a = t1[slot] / fmaxf((float)tc[slot], 1.0f);
        float v = a * W1l[f] + b1[f] + x[n] * W1r[f];
        h1b[(size_t)n * 64 + f] = f2bf(fmaxf(v, 0.0f));
    }
}

// ---- layer 2 fused: gather-aggregate (explicit-scalar ILP, NO arrays) +
//      LDS-weight GEMV + relu + mean-pool.  LDS = 8KB tile + 32KB weights.
__global__ __launch_bounds__(256) void k_l2(
    const int* __restrict__ bh, const unsigned int* __restrict__ bins,
    const unsigned short* __restrict__ h1b, const int* __restrict__ cnt,
    const float* __restrict__ W2l, const float* __restrict__ b2,
    const float* __restrict__ W2r,
    const int* __restrict__ batch, const float* __restrict__ gcnt,
    float* __restrict__ pooled) {
    __shared__ float tile[TILE_N * 64];        // 8 KB
    __shared__ float wl[64 * 64];              // 16 KB
    __shared__ float wr[64 * 64];              // 16 KB
    int k = blockIdx.x;
    int f = threadIdx.x & 63;
    int wid = threadIdx.x >> 6;
    for (int i = threadIdx.x; i < TILE_N * 64; i += 256) tile[i] = 0.0f;
    for (int i = threadIdx.x; i < 4096; i += 256) { wl[i] = W2l[i]; wr[i] = W2r[i]; }
    __syncthreads();

    int cc = min(bh[k], BSTRIDE);
    const unsigned int* bb = bins + (size_t)k * BSTRIDE;
    for (int g = wid * 64; g < cc; g += 256) {
        int idx = g + f;
        unsigned p = (idx < cc) ? bb[idx] : 0u;
        int d = (int)(p & 31u);
        int s = (int)(p >> 5);
        int c = min(64, cc - g);
        int j = 0;
        for (; j + 8 <= c; j += 8) {
            // explicit scalars: 8 independent gathers truly in flight
            int s0 = __builtin_amdgcn_readlane(s, j + 0);
            int s1 = __builtin_amdgcn_readlane(s, j + 1);
            int s2 = __builtin_amdgcn_readlane(s, j + 2);
            int s3 = __builtin_amdgcn_readlane(s, j + 3);
            int s4 = __builtin_amdgcn_readlane(s, j + 4);
            int s5 = __builtin_amdgcn_readlane(s, j + 5);
            int s6 = __builtin_amdgcn_readlane(s, j + 6);
            int s7 = __builtin_amdgcn_readlane(s, j + 7);
            float v0 = bf2f(h1b[(size_t)s0 * 64 + f]);
            float v1 = bf2f(h1b[(size_t)s1 * 64 + f]);
            float v2 = bf2f(h1b[(size_t)s2 * 64 + f]);
            float v3 = bf2f(h1b[(size_t)s3 * 64 + f]);
            float v4 = bf2f(h1b[(size_t)s4 * 64 + f]);
            float v5 = bf2f(h1b[(size_t)s5 * 64 + f]);
            float v6 = bf2f(h1b[(size_t)s6 * 64 + f]);
            float v7 = bf2f(h1b[(size_t)s7 * 64 + f]);
            int d0 = __builtin_amdgcn_readlane(d, j + 0);
            int d1 = __builtin_amdgcn_readlane(d, j + 1);
            int d2 = __builtin_amdgcn_readlane(d, j + 2);
            int d3 = __builtin_amdgcn_readlane(d, j + 3);
            int d4 = __builtin_amdgcn_readlane(d, j + 4);
            int d5 = __builtin_amdgcn_readlane(d, j + 5);
            int d6 = __builtin_amdgcn_readlane(d, j + 6);
            int d7 = __builtin_amdgcn_readlane(d, j + 7);
            atomicAdd(&tile[d0 * 64 + f], v0);
            atomicAdd(&tile[d1 * 64 + f], v1);
            atomicAdd(&tile[d2 * 64 + f], v2);
            atomicAdd(&tile[d3 * 64 + f], v3);
            atomicAdd(&tile[d4 * 64 + f], v4);
            atomicAdd(&tile[d5 * 64 + f], v5);
            atomicAdd(&tile[d6 * 64 + f], v6);
            atomicAdd(&tile[d7 * 64 + f], v7);
        }
        for (; j < c; ++j) {
            int sj = __builtin_amdgcn_readlane(s, j);
            int dj = __builtin_amdgcn_readlane(d, j);
            atomicAdd(&tile[dj * 64 + f], bf2f(h1b[(size_t)sj * 64 + f]));
        }
    }
    __syncthreads();

    float bias = b2[f];
    for (int t = wid; t < TILE_N; t += 4) {
        int n = k * TILE_N + t;
        float m = tile[t * 64 + f] / fmaxf((float)cnt[n], 1.0f);
        float h = bf2f(h1b[(size_t)n * 64 + f]);
        float acc = bias;
#pragma unroll
        for (int kk = 0; kk < 64; kk++) {
            acc += rlanef(m, kk) * wl[kk * 64 + f];   // 2-way bank = free
            acc += rlanef(h, kk) * wr[kk * 64 + f];
        }
        acc = fmaxf(acc, 0.0f);
        int b = batch[n];
        atomicAdd(&pooled[b * 64 + f], acc / fmaxf(gcnt[b], 1.0f));
    }
}

// ---- classifier ----
__global__ void k_cls(const float* __restrict__ pooled, const float* __restrict__ Wc,
                      const float* __restrict__ bc, float* __restrict__ out) {
    __shared__ float rowv[64];
    int g = blockIdx.x;
    int f = threadIdx.x;
    rowv[f] = pooled[g * 64 + f];
    __syncthreads();
    if (f < NCLS) {
        float acc = bc[f];
#pragma unroll
        for (int kk = 0; kk < 64; kk++) acc += rowv[kk] * Wc[kk * NCLS + f];
        out[g * NCLS + f] = acc;
    }
}

extern "C" void kernel_launch(void* const* d_in, const int* in_sizes, int n_in,
                              void* d_out, int out_size, void* d_ws, size_t ws_size,
                              hipStream_t stream) {
    const float* x     = (const float*)d_in[0];
    const int*   eidx  = (const int*)d_in[1];
    const int*   batch = (const int*)d_in[2];
    const float* W1l   = (const float*)d_in[3];
    const float* b1    = (const float*)d_in[4];
    const float* W1r   = (const float*)d_in[5];
    const float* W2l   = (const float*)d_in[6];
    const float* b2    = (const float*)d_in[7];
    const float* W2r   = (const float*)d_in[8];
    const float* Wc    = (const float*)d_in[9];
    const float* bc    = (const float*)d_in[10];
    float* out = (float*)d_out;

    const int* src = eidx;
    const int* dst = eidx + N_EDGES;

    // workspace: 25.6 + 12.8 + 0.4 + ~0.28 MB = 39.1 MB (< proven-safe 40.27)
    char* p = (char*)d_ws;
    unsigned int*   bins = (unsigned int*)p;   p += (size_t)K_BUCKETS * BSTRIDE * 4;
    unsigned short* h1b  = (unsigned short*)p; p += (size_t)N_NODES * 64 * 2;
    int*   cnt    = (int*)p;                   p += (size_t)N_NODES * 4;
    // ---- zeroed region (contiguous) ----
    int*   bh     = (int*)p;                   p += K_BUCKETS * 4;
    float* gcnt   = (float*)p;                 p += N_GRAPHS * 4;
    float* pooled = (float*)p;                 p += (size_t)N_GRAPHS * 64 * 4;
    size_t zero_bytes = (size_t)(K_BUCKETS + N_GRAPHS + N_GRAPHS * 64) * 4;

    hipMemsetAsync(bh, 0, zero_bytes, stream);

    k_bin2 <<<1024, 256, 0, stream>>>(src, dst, bh, bins);
    k_l1agg<<<K_BUCKETS, 256, 0, stream>>>(bh, bins, x, W1l, b1, W1r,
                                           batch, gcnt, h1b, cnt);
    k_l2   <<<K_BUCKETS, 256, 0, stream>>>(bh, bins, h1b, cnt, W2l, b2, W2r,
                                           batch, gcnt, pooled);
    k_cls  <<<N_GRAPHS, 64, 0, stream>>>(pooled, Wc, bc, out);
}

// Round 7
// 766.932 us; speedup vs baseline: 2.1457x; 2.0222x over previous
//
#include <hip/hip_runtime.h>

#define N_NODES 100000
#define N_EDGES 3200000
#define N_GRAPHS 1024
#define NCLS 21
#define SCAN_NB 98   // ceil(100000/1024)

__device__ __forceinline__ float rlanef(float v, int l) {
    return __int_as_float(__builtin_amdgcn_readlane(__float_as_int(v), l));
}
__device__ __forceinline__ float bf2f(unsigned short u) {
    return __uint_as_float(((unsigned)u) << 16);
}
__device__ __forceinline__ unsigned short f2bf(float f) {
    unsigned u = __float_as_uint(f);
    unsigned r = 0x7fffu + ((u >> 16) & 1u);   // RNE
    return (unsigned short)((u + r) >> 16);
}

// ---- degree histogram ----
__global__ void k_deg(const int* __restrict__ dst, int* __restrict__ deg) {
    int e = blockIdx.x * 256 + threadIdx.x;
    if (e < N_EDGES) atomicAdd(&deg[dst[e]], 1);
}

// ---- exclusive scan deg -> row (3 kernels) ----
__global__ void k_scan1(const int* __restrict__ deg, int* __restrict__ row,
                        int* __restrict__ bsum) {
    __shared__ int lds[256];
    int t = threadIdx.x;
    int base = blockIdx.x * 1024 + t * 4;
    int v[4];
#pragma unroll
    for (int i = 0; i < 4; i++) v[i] = (base + i < N_NODES) ? deg[base + i] : 0;
    int tsum = v[0] + v[1] + v[2] + v[3];
    lds[t] = tsum;
    __syncthreads();
    for (int off = 1; off < 256; off <<= 1) {
        int cur = lds[t];
        int add = (t >= off) ? lds[t - off] : 0;
        __syncthreads();
        lds[t] = cur + add;
        __syncthreads();
    }
    int run = lds[t] - tsum;
#pragma unroll
    for (int i = 0; i < 4; i++) {
        if (base + i < N_NODES) row[base + i] = run;
        run += v[i];
    }
    if (t == 255) bsum[blockIdx.x] = lds[255];
}

__global__ void k_scan2(int* __restrict__ bsum) {
    if (threadIdx.x == 0 && blockIdx.x == 0) {
        int acc = 0;
        for (int b = 0; b < SCAN_NB; b++) { int t = bsum[b]; bsum[b] = acc; acc += t; }
    }
}

__global__ void k_scan3(int* __restrict__ row, const int* __restrict__ bsum,
                        int* __restrict__ cursor) {
    int i = blockIdx.x * 256 + threadIdx.x;
    if (i < N_NODES) {
        int r = row[i] + bsum[i >> 10];
        row[i] = r;
        cursor[i] = r;
    }
    if (i == 0) row[N_NODES] = N_EDGES;
}

// ---- scatter src into per-node CSR ----
__global__ void k_scatter(const int* __restrict__ src, const int* __restrict__ dst,
                          int* __restrict__ cursor, int* __restrict__ csr) {
    int e = blockIdx.x * 256 + threadIdx.x;
    if (e < N_EDGES) {
        int pos = atomicAdd(&cursor[dst[e]], 1);
        csr[pos] = src[e];
    }
}

// ---- layer 1: wave per node, register reduce, linear+relu -> h1b (bf16) ----
__global__ __launch_bounds__(256) void k_l1(
    const int* __restrict__ row, const int* __restrict__ csr,
    const float* __restrict__ x,
    const float* __restrict__ W1l, const float* __restrict__ b1,
    const float* __restrict__ W1r,
    const int* __restrict__ batch, float* __restrict__ gcnt,
    unsigned short* __restrict__ h1b) {
    int n = (blockIdx.x * 256 + threadIdx.x) >> 6;
    int f = threadIdx.x & 63;
    if (n >= N_NODES) return;
    int r0 = row[n], r1 = row[n + 1];
    float s = 0.0f;
    for (int idx = r0 + f; idx < r1; idx += 64) s += x[csr[idx]];
#pragma unroll
    for (int off = 32; off; off >>= 1) s += __shfl_xor(s, off);
    float agg = s / fmaxf((float)(r1 - r0), 1.0f);
    float v = agg * W1l[f] + b1[f] + x[n] * W1r[f];
    h1b[(size_t)n * 64 + f] = f2bf(fmaxf(v, 0.0f));
    if (f == 0) atomicAdd(&gcnt[batch[n]], 1.0f);
}

// ---- layer 2 gather: wave per node, REGISTER accumulate (no LDS atomics) ----
__global__ __launch_bounds__(256) void k_gather2(
    const int* __restrict__ row, const int* __restrict__ csr,
    const unsigned short* __restrict__ h1b,
    unsigned short* __restrict__ agg2b) {
    int gw = (blockIdx.x * 256 + threadIdx.x) >> 6;
    int f = threadIdx.x & 63;
    int nw = gridDim.x * 4;
    for (int n = gw; n < N_NODES; n += nw) {
        int r0 = row[n], r1 = row[n + 1];
        float s = 0.0f;
        for (int base = r0; base < r1; base += 64) {
            int idx = base + f;
            int vs = (idx < r1) ? csr[idx] : 0;
            int c = min(64, r1 - base);
            int j = 0;
            for (; j + 8 <= c; j += 8) {
                int a0 = __builtin_amdgcn_readlane(vs, j + 0);
                int a1 = __builtin_amdgcn_readlane(vs, j + 1);
                int a2 = __builtin_amdgcn_readlane(vs, j + 2);
                int a3 = __builtin_amdgcn_readlane(vs, j + 3);
                int a4 = __builtin_amdgcn_readlane(vs, j + 4);
                int a5 = __builtin_amdgcn_readlane(vs, j + 5);
                int a6 = __builtin_amdgcn_readlane(vs, j + 6);
                int a7 = __builtin_amdgcn_readlane(vs, j + 7);
                float v0 = bf2f(h1b[(size_t)a0 * 64 + f]);
                float v1 = bf2f(h1b[(size_t)a1 * 64 + f]);
                float v2 = bf2f(h1b[(size_t)a2 * 64 + f]);
                float v3 = bf2f(h1b[(size_t)a3 * 64 + f]);
                float v4 = bf2f(h1b[(size_t)a4 * 64 + f]);
                float v5 = bf2f(h1b[(size_t)a5 * 64 + f]);
                float v6 = bf2f(h1b[(size_t)a6 * 64 + f]);
                float v7 = bf2f(h1b[(size_t)a7 * 64 + f]);
                s += ((v0 + v1) + (v2 + v3)) + ((v4 + v5) + (v6 + v7));
            }
            for (; j < c; ++j) {
                int aj = __builtin_amdgcn_readlane(vs, j);
                s += bf2f(h1b[(size_t)aj * 64 + f]);
            }
        }
        float m = s / fmaxf((float)(r1 - r0), 1.0f);
        agg2b[(size_t)n * 64 + f] = f2bf(m);
    }
}

// ---- layer 2 GEMV: LDS weights, readlane broadcast, relu + mean-pool ----
__global__ __launch_bounds__(256) void k_gemv(
    const unsigned short* __restrict__ agg2b, const unsigned short* __restrict__ h1b,
    const float* __restrict__ W2l, const float* __restrict__ b2,
    const float* __restrict__ W2r,
    const int* __restrict__ batch, const float* __restrict__ gcnt,
    float* __restrict__ pooled) {
    __shared__ float wl[4096];   // 16 KB
    __shared__ float wr[4096];   // 16 KB
    for (int i = threadIdx.x; i < 4096; i += 256) { wl[i] = W2l[i]; wr[i] = W2r[i]; }
    __syncthreads();
    int f = threadIdx.x & 63;
    int wid = threadIdx.x >> 6;
    float bias = b2[f];
    int n0 = blockIdx.x * 64 + wid * 16;
    for (int t = 0; t < 16; t++) {
        int n = n0 + t;
        if (n >= N_NODES) break;
        float m = bf2f(agg2b[(size_t)n * 64 + f]);
        float h = bf2f(h1b[(size_t)n * 64 + f]);
        float acc = bias;
#pragma unroll
        for (int kk = 0; kk < 64; kk++) {
            acc += rlanef(m, kk) * wl[kk * 64 + f];   // 2-way bank = free
            acc += rlanef(h, kk) * wr[kk * 64 + f];
        }
        acc = fmaxf(acc, 0.0f);
        int b = batch[n];
        atomicAdd(&pooled[b * 64 + f], acc / fmaxf(gcnt[b], 1.0f));
    }
}

// ---- classifier ----
__global__ void k_cls(const float* __restrict__ pooled, const float* __restrict__ Wc,
                      const float* __restrict__ bc, float* __restrict__ out) {
    __shared__ float rowv[64];
    int g = blockIdx.x;
    int f = threadIdx.x;
    rowv[f] = pooled[g * 64 + f];
    __syncthreads();
    if (f < NCLS) {
        float acc = bc[f];
#pragma unroll
        for (int kk = 0; kk < 64; kk++) acc += rowv[kk] * Wc[kk * NCLS + f];
        out[g * NCLS + f] = acc;
    }
}

extern "C" void kernel_launch(void* const* d_in, const int* in_sizes, int n_in,
                              void* d_out, int out_size, void* d_ws, size_t ws_size,
                              hipStream_t stream) {
    const float* x     = (const float*)d_in[0];
    const int*   eidx  = (const int*)d_in[1];
    const int*   batch = (const int*)d_in[2];
    const float* W1l   = (const float*)d_in[3];
    const float* b1    = (const float*)d_in[4];
    const float* W1r   = (const float*)d_in[5];
    const float* W2l   = (const float*)d_in[6];
    const float* b2    = (const float*)d_in[7];
    const float* W2r   = (const float*)d_in[8];
    const float* Wc    = (const float*)d_in[9];
    const float* bc    = (const float*)d_in[10];
    float* out = (float*)d_out;

    const int* src = eidx;
    const int* dst = eidx + N_EDGES;

    // workspace: csr 12.8 + h1b 12.8 + agg2b 12.8 + row/cursor/deg 1.2 + misc
    //  ≈ 39.9 MB  (R1 passed with 40.67 MB)
    char* p = (char*)d_ws;
    int* csr             = (int*)p;            p += (size_t)N_EDGES * 4;
    unsigned short* h1b  = (unsigned short*)p; p += (size_t)N_NODES * 64 * 2;
    unsigned short* agg2b= (unsigned short*)p; p += (size_t)N_NODES * 64 * 2;
    int* row             = (int*)p;            p += (size_t)(N_NODES + 1) * 4;
    int* cursor          = (int*)p;            p += (size_t)N_NODES * 4;
    int* bsum            = (int*)p;            p += 128 * 4;
    // ---- zeroed region (contiguous) ----
    int*   deg    = (int*)p;                   p += (size_t)N_NODES * 4;
    float* gcnt   = (float*)p;                 p += N_GRAPHS * 4;
    float* pooled = (float*)p;                 p += (size_t)N_GRAPHS * 64 * 4;
    size_t zero_bytes = (size_t)(N_NODES + N_GRAPHS + N_GRAPHS * 64) * 4;

    hipMemsetAsync(deg, 0, zero_bytes, stream);

    k_deg    <<<(N_EDGES + 255) / 256, 256, 0, stream>>>(dst, deg);
    k_scan1  <<<SCAN_NB, 256, 0, stream>>>(deg, row, bsum);
    k_scan2  <<<1, 64, 0, stream>>>(bsum);
    k_scan3  <<<(N_NODES + 255) / 256, 256, 0, stream>>>(row, bsum, cursor);
    k_scatter<<<(N_EDGES + 255) / 256, 256, 0, stream>>>(src, dst, cursor, csr);

    k_l1     <<<(N_NODES * 64 + 255) / 256, 256, 0, stream>>>(row, csr, x, W1l, b1, W1r,
                                                              batch, gcnt, h1b);
    k_gather2<<<2048, 256, 0, stream>>>(row, csr, h1b, agg2b);
    k_gemv   <<<(N_NODES + 63) / 64, 256, 0, stream>>>(agg2b, h1b, W2l, b2, W2r,
                                                       batch, gcnt, pooled);
    k_cls    <<<N_GRAPHS, 64, 0, stream>>>(pooled, Wc, bc, out);
}

// Round 8
// 455.693 us; speedup vs baseline: 3.6111x; 1.6830x over previous
//
#include <hip/hip_runtime.h>

#define N_NODES 100000
#define N_EDGES 3200000
#define N_GRAPHS 1024
#define NCLS 21
#define NBKT 196          // buckets of 512 nodes: ceil(100000/512)
#define NB 256            // streaming blocks
#define CHUNK 12500       // N_EDGES / NB
#define SCAN_N (NBKT*NB)  // 50176
#define SCAN_NB1 49       // SCAN_N / 1024
#define BUF_CAP 24576     // 96KB LDS edge buffer (mean 16326, sigma 127 -> +65 sigma)

__device__ __forceinline__ float rlanef(float v, int l) {
    return __int_as_float(__builtin_amdgcn_readlane(__float_as_int(v), l));
}
__device__ __forceinline__ float bf2f(unsigned short u) {
    return __uint_as_float(((unsigned)u) << 16);
}
__device__ __forceinline__ unsigned short f2bf(float f) {
    unsigned u = __float_as_uint(f);
    unsigned r = 0x7fffu + ((u >> 16) & 1u);   // RNE
    return (unsigned short)((u + r) >> 16);
}

// ---- per-block bucket histogram: gh[bucket*NB + block] (fully written) ----
__global__ __launch_bounds__(256) void k_hist(const int* __restrict__ dst,
                                              int* __restrict__ gh) {
    __shared__ int lh[NBKT];
    for (int i = threadIdx.x; i < NBKT; i += 256) lh[i] = 0;
    __syncthreads();
    int e0 = blockIdx.x * CHUNK;
    for (int e = e0 + threadIdx.x; e < e0 + CHUNK; e += 256)
        atomicAdd(&lh[dst[e] >> 9], 1);
    __syncthreads();
    for (int i = threadIdx.x; i < NBKT; i += 256) gh[i * NB + blockIdx.x] = lh[i];
}

// ---- exclusive scan over gh, in place (3 kernels) ----
__global__ void k_scan1(int* __restrict__ buf, int* __restrict__ bsum) {
    __shared__ int lds[256];
    int t = threadIdx.x;
    int base = blockIdx.x * 1024 + t * 4;
    int v[4];
#pragma unroll
    for (int i = 0; i < 4; i++) v[i] = buf[base + i];   // SCAN_N % 1024 == 0
    int tsum = v[0] + v[1] + v[2] + v[3];
    lds[t] = tsum;
    __syncthreads();
    for (int off = 1; off < 256; off <<= 1) {
        int cur = lds[t];
        int add = (t >= off) ? lds[t - off] : 0;
        __syncthreads();
        lds[t] = cur + add;
        __syncthreads();
    }
    int run = lds[t] - tsum;
#pragma unroll
    for (int i = 0; i < 4; i++) { buf[base + i] = run; run += v[i]; }
    if (t == 255) bsum[blockIdx.x] = lds[255];
}

__global__ void k_scan2(int* __restrict__ bsum) {
    if (threadIdx.x == 0 && blockIdx.x == 0) {
        int acc = 0;
        for (int b = 0; b < SCAN_NB1; b++) { int t = bsum[b]; bsum[b] = acc; acc += t; }
    }
}

__global__ void k_scan3(int* __restrict__ buf, const int* __restrict__ bsum) {
    int i = blockIdx.x * 256 + threadIdx.x;
    if (i < SCAN_N) buf[i] += bsum[i >> 10];
}

// ---- bin edges into bucket-grouped runs (deterministic, LDS cursors) ----
// payload: (src << 9) | (dst & 511)
__global__ __launch_bounds__(256) void k_bin(const int* __restrict__ src,
                                             const int* __restrict__ dst,
                                             const int* __restrict__ S,
                                             unsigned int* __restrict__ bins) {
    __shared__ int cur[NBKT];
    for (int i = threadIdx.x; i < NBKT; i += 256) cur[i] = S[i * NB + blockIdx.x];
    __syncthreads();
    int e0 = blockIdx.x * CHUNK;
    for (int e = e0 + threadIdx.x; e < e0 + CHUNK; e += 256) {
        int dd = dst[e];
        int pos = atomicAdd(&cur[dd >> 9], 1);
        bins[pos] = ((unsigned)src[e] << 9) | (unsigned)(dd & 511);
    }
}

// ---- per-bucket: LDS slurp -> degree hist -> block scan -> row[] + in-place CSR ----
__global__ __launch_bounds__(256) void k_build(const int* __restrict__ S,
                                               unsigned int* __restrict__ bins,
                                               int* __restrict__ row) {
    __shared__ unsigned int ebuf[BUF_CAP];   // 96 KB
    __shared__ int hist[512];
    __shared__ int curs[512];
    __shared__ int lds[256];
    int k = blockIdx.x, t = threadIdx.x;
    int e0 = S[k * NB];
    int e1 = (k == NBKT - 1) ? N_EDGES : S[(k + 1) * NB];
    int cnt = min(e1 - e0, BUF_CAP);
    hist[t] = 0; hist[t + 256] = 0;
    __syncthreads();
    for (int i = t; i < cnt; i += 256) {
        unsigned p = bins[e0 + i];
        ebuf[i] = p;
        atomicAdd(&hist[p & 511u], 1);
    }
    __syncthreads();
    int h0 = hist[2 * t], h1 = hist[2 * t + 1];
    lds[t] = h0 + h1;
    __syncthreads();
    for (int off = 1; off < 256; off <<= 1) {
        int cur = lds[t];
        int add = (t >= off) ? lds[t - off] : 0;
        __syncthreads();
        lds[t] = cur + add;
        __syncthreads();
    }
    int run = e0 + lds[t] - (h0 + h1);   // exclusive start for local node 2t
    curs[2 * t] = run;
    curs[2 * t + 1] = run + h0;
    int n0 = k * 512 + 2 * t;
    if (n0 < N_NODES) row[n0] = run;
    if (n0 + 1 < N_NODES) row[n0 + 1] = run + h0;
    if (k == NBKT - 1 && t == 255) row[N_NODES] = N_EDGES;
    __syncthreads();
    for (int i = t; i < cnt; i += 256) {
        unsigned p = ebuf[i];
        int pos = atomicAdd(&curs[p & 511u], 1);
        bins[pos] = p >> 9;              // in-place: now exact CSR (src ids)
    }
}

// ---- layer 1: wave per node, register reduce, linear+relu -> h1b (bf16) ----
__global__ __launch_bounds__(256) void k_l1(
    const int* __restrict__ row, const unsigned int* __restrict__ csr,
    const float* __restrict__ x,
    const float* __restrict__ W1l, const float* __restrict__ b1,
    const float* __restrict__ W1r,
    const int* __restrict__ batch, float* __restrict__ gcnt,
    unsigned short* __restrict__ h1b) {
    int n = (blockIdx.x * 256 + threadIdx.x) >> 6;
    int f = threadIdx.x & 63;
    if (n >= N_NODES) return;
    int r0 = row[n], r1 = row[n + 1];
    float s = 0.0f;
    for (int idx = r0 + f; idx < r1; idx += 64) s += x[csr[idx]];
#pragma unroll
    for (int off = 32; off; off >>= 1) s += __shfl_xor(s, off);
    float agg = s / fmaxf((float)(r1 - r0), 1.0f);
    float v = agg * W1l[f] + b1[f] + x[n] * W1r[f];
    h1b[(size_t)n * 64 + f] = f2bf(fmaxf(v, 0.0f));
    if (f == 0) atomicAdd(&gcnt[batch[n]], 1.0f);
}

// ---- layer 2 gather: wave per node, register accumulate ----
__global__ __launch_bounds__(256) void k_gather2(
    const int* __restrict__ row, const unsigned int* __restrict__ csr,
    const unsigned short* __restrict__ h1b,
    unsigned short* __restrict__ agg2b) {
    int gw = (blockIdx.x * 256 + threadIdx.x) >> 6;
    int f = threadIdx.x & 63;
    int nw = gridDim.x * 4;
    for (int n = gw; n < N_NODES; n += nw) {
        int r0 = row[n], r1 = row[n + 1];
        float s = 0.0f;
        for (int base = r0; base < r1; base += 64) {
            int idx = base + f;
            int vs = (idx < r1) ? (int)csr[idx] : 0;
            int c = min(64, r1 - base);
            int j = 0;
            for (; j + 8 <= c; j += 8) {
                int a0 = __builtin_amdgcn_readlane(vs, j + 0);
                int a1 = __builtin_amdgcn_readlane(vs, j + 1);
                int a2 = __builtin_amdgcn_readlane(vs, j + 2);
                int a3 = __builtin_amdgcn_readlane(vs, j + 3);
                int a4 = __builtin_amdgcn_readlane(vs, j + 4);
                int a5 = __builtin_amdgcn_readlane(vs, j + 5);
                int a6 = __builtin_amdgcn_readlane(vs, j + 6);
                int a7 = __builtin_amdgcn_readlane(vs, j + 7);
                float v0 = bf2f(h1b[(size_t)a0 * 64 + f]);
                float v1 = bf2f(h1b[(size_t)a1 * 64 + f]);
                float v2 = bf2f(h1b[(size_t)a2 * 64 + f]);
                float v3 = bf2f(h1b[(size_t)a3 * 64 + f]);
                float v4 = bf2f(h1b[(size_t)a4 * 64 + f]);
                float v5 = bf2f(h1b[(size_t)a5 * 64 + f]);
                float v6 = bf2f(h1b[(size_t)a6 * 64 + f]);
                float v7 = bf2f(h1b[(size_t)a7 * 64 + f]);
                s += ((v0 + v1) + (v2 + v3)) + ((v4 + v5) + (v6 + v7));
            }
            for (; j < c; ++j) {
                int aj = __builtin_amdgcn_readlane(vs, j);
                s += bf2f(h1b[(size_t)aj * 64 + f]);
            }
        }
        float m = s / fmaxf((float)(r1 - r0), 1.0f);
        agg2b[(size_t)n * 64 + f] = f2bf(m);
    }
}

// ---- layer 2 GEMV: LDS weights, readlane broadcast, relu + mean-pool ----
__global__ __launch_bounds__(256) void k_gemv(
    const unsigned short* __restrict__ agg2b, const unsigned short* __restrict__ h1b,
    const float* __restrict__ W2l, const float* __restrict__ b2,
    const float* __restrict__ W2r,
    const int* __restrict__ batch, const float* __restrict__ gcnt,
    float* __restrict__ pooled) {
    __shared__ float wl[4096];   // 16 KB
    __shared__ float wr[4096];   // 16 KB
    for (int i = threadIdx.x; i < 4096; i += 256) { wl[i] = W2l[i]; wr[i] = W2r[i]; }
    __syncthreads();
    int f = threadIdx.x & 63;
    int wid = threadIdx.x >> 6;
    float bias = b2[f];
    int n0 = blockIdx.x * 64 + wid * 16;
    for (int t = 0; t < 16; t++) {
        int n = n0 + t;
        if (n >= N_NODES) break;
        float m = bf2f(agg2b[(size_t)n * 64 + f]);
        float h = bf2f(h1b[(size_t)n * 64 + f]);
        float acc = bias;
#pragma unroll
        for (int kk = 0; kk < 64; kk++) {
            acc += rlanef(m, kk) * wl[kk * 64 + f];
            acc += rlanef(h, kk) * wr[kk * 64 + f];
        }
        acc = fmaxf(acc, 0.0f);
        int b = batch[n];
        atomicAdd(&pooled[b * 64 + f], acc / fmaxf(gcnt[b], 1.0f));
    }
}

// ---- classifier ----
__global__ void k_cls(const float* __restrict__ pooled, const float* __restrict__ Wc,
                      const float* __restrict__ bc, float* __restrict__ out) {
    __shared__ float rowv[64];
    int g = blockIdx.x;
    int f = threadIdx.x;
    rowv[f] = pooled[g * 64 + f];
    __syncthreads();
    if (f < NCLS) {
        float acc = bc[f];
#pragma unroll
        for (int kk = 0; kk < 64; kk++) acc += rowv[kk] * Wc[kk * NCLS + f];
        out[g * NCLS + f] = acc;
    }
}

extern "C" void kernel_launch(void* const* d_in, const int* in_sizes, int n_in,
                              void* d_out, int out_size, void* d_ws, size_t ws_size,
                              hipStream_t stream) {
    const float* x     = (const float*)d_in[0];
    const int*   eidx  = (const int*)d_in[1];
    const int*   batch = (const int*)d_in[2];
    const float* W1l   = (const float*)d_in[3];
    const float* b1    = (const float*)d_in[4];
    const float* W1r   = (const float*)d_in[5];
    const float* W2l   = (const float*)d_in[6];
    const float* b2    = (const float*)d_in[7];
    const float* W2r   = (const float*)d_in[8];
    const float* Wc    = (const float*)d_in[9];
    const float* bc    = (const float*)d_in[10];
    float* out = (float*)d_out;

    const int* src = eidx;
    const int* dst = eidx + N_EDGES;

    // workspace: bins/csr 12.8 + h1b 12.8 + agg2b 12.8 + gh 0.2 + row 0.4 ≈ 39.1 MB
    char* p = (char*)d_ws;
    unsigned int* bins    = (unsigned int*)p;   p += (size_t)N_EDGES * 4;
    unsigned short* h1b   = (unsigned short*)p; p += (size_t)N_NODES * 64 * 2;
    unsigned short* agg2b = (unsigned short*)p; p += (size_t)N_NODES * 64 * 2;
    int* gh   = (int*)p;                        p += (size_t)SCAN_N * 4;
    int* bsum = (int*)p;                        p += 64 * 4;
    int* row  = (int*)p;                        p += (size_t)(N_NODES + 1) * 4;
    // ---- zeroed region (contiguous) ----
    float* gcnt   = (float*)p;                  p += N_GRAPHS * 4;
    float* pooled = (float*)p;                  p += (size_t)N_GRAPHS * 64 * 4;
    size_t zero_bytes = (size_t)(N_GRAPHS + N_GRAPHS * 64) * 4;

    hipMemsetAsync(gcnt, 0, zero_bytes, stream);

    k_hist <<<NB, 256, 0, stream>>>(dst, gh);
    k_scan1<<<SCAN_NB1, 256, 0, stream>>>(gh, bsum);
    k_scan2<<<1, 64, 0, stream>>>(bsum);
    k_scan3<<<(SCAN_N + 255) / 256, 256, 0, stream>>>(gh, bsum);
    k_bin  <<<NB, 256, 0, stream>>>(src, dst, gh, bins);
    k_build<<<NBKT, 256, 0, stream>>>(gh, bins, row);

    k_l1     <<<(N_NODES * 64 + 255) / 256, 256, 0, stream>>>(row, bins, x, W1l, b1, W1r,
                                                              batch, gcnt, h1b);
    k_gather2<<<2048, 256, 0, stream>>>(row, bins, h1b, agg2b);
    k_gemv   <<<(N_NODES + 63) / 64, 256, 0, stream>>>(agg2b, h1b, W2l, b2, W2r,
                                                       batch, gcnt, pooled);
    k_cls    <<<N_GRAPHS, 64, 0, stream>>>(pooled, Wc, bc, out);
}

// Round 9
// 363.705 us; speedup vs baseline: 4.5245x; 1.2529x over previous
//
#include <hip/hip_runtime.h>

#define N_NODES 100000
#define N_EDGES 3200000
#define N_GRAPHS 1024
#define NCLS 21
#define NBKT 196          // buckets of 512 nodes: ceil(100000/512)
#define NB 256            // streaming blocks
#define CHUNK 12500       // N_EDGES / NB
#define SCAN_N (NBKT*NB)  // 50176
#define SCAN_NB1 49       // SCAN_N / 1024
#define BUF_CAP 24576     // 96KB LDS edge buffer (mean 16326, sigma 127 -> +65 sigma)

__device__ __forceinline__ float rlanef(float v, int l) {
    return __int_as_float(__builtin_amdgcn_readlane(__float_as_int(v), l));
}
__device__ __forceinline__ float bf2f(unsigned short u) {
    return __uint_as_float(((unsigned)u) << 16);
}
__device__ __forceinline__ unsigned short f2bf(float f) {
    unsigned u = __float_as_uint(f);
    unsigned r = 0x7fffu + ((u >> 16) & 1u);   // RNE
    return (unsigned short)((u + r) >> 16);
}

// ---- per-graph node counts: batch is SORTED -> binary search, zero atomics ----
__global__ void k_gcnt(const int* __restrict__ batch, float* __restrict__ gcnt) {
    int g = blockIdx.x * 256 + threadIdx.x;
    if (g >= N_GRAPHS) return;
    int lo = 0, hi = N_NODES;
    while (lo < hi) { int m = (lo + hi) >> 1; if (batch[m] < g) lo = m + 1; else hi = m; }
    int lo2 = lo, hi2 = N_NODES;
    while (lo2 < hi2) { int m = (lo2 + hi2) >> 1; if (batch[m] < g + 1) lo2 = m + 1; else hi2 = m; }
    gcnt[g] = (float)(lo2 - lo);
}

// ---- per-block bucket histogram: gh[bucket*NB + block] (fully written) ----
__global__ __launch_bounds__(256) void k_hist(const int* __restrict__ dst,
                                              int* __restrict__ gh) {
    __shared__ int lh[NBKT];
    for (int i = threadIdx.x; i < NBKT; i += 256) lh[i] = 0;
    __syncthreads();
    int e0 = blockIdx.x * CHUNK;
    for (int e = e0 + threadIdx.x; e < e0 + CHUNK; e += 256)
        atomicAdd(&lh[dst[e] >> 9], 1);
    __syncthreads();
    for (int i = threadIdx.x; i < NBKT; i += 256) gh[i * NB + blockIdx.x] = lh[i];
}

// ---- exclusive scan over gh, in place (3 kernels) ----
__global__ void k_scan1(int* __restrict__ buf, int* __restrict__ bsum) {
    __shared__ int lds[256];
    int t = threadIdx.x;
    int base = blockIdx.x * 1024 + t * 4;
    int v[4];
#pragma unroll
    for (int i = 0; i < 4; i++) v[i] = buf[base + i];   // SCAN_N % 1024 == 0
    int tsum = v[0] + v[1] + v[2] + v[3];
    lds[t] = tsum;
    __syncthreads();
    for (int off = 1; off < 256; off <<= 1) {
        int cur = lds[t];
        int add = (t >= off) ? lds[t - off] : 0;
        __syncthreads();
        lds[t] = cur + add;
        __syncthreads();
    }
    int run = lds[t] - tsum;
#pragma unroll
    for (int i = 0; i < 4; i++) { buf[base + i] = run; run += v[i]; }
    if (t == 255) bsum[blockIdx.x] = lds[255];
}

__global__ void k_scan2(int* __restrict__ bsum) {
    if (threadIdx.x == 0 && blockIdx.x == 0) {
        int acc = 0;
        for (int b = 0; b < SCAN_NB1; b++) { int t = bsum[b]; bsum[b] = acc; acc += t; }
    }
}

__global__ void k_scan3(int* __restrict__ buf, const int* __restrict__ bsum) {
    int i = blockIdx.x * 256 + threadIdx.x;
    if (i < SCAN_N) buf[i] += bsum[i >> 10];
}

// ---- bin edges into bucket-grouped runs (deterministic, LDS cursors) ----
// payload: (src << 9) | (dst & 511)
__global__ __launch_bounds__(256) void k_bin(const int* __restrict__ src,
                                             const int* __restrict__ dst,
                                             const int* __restrict__ S,
                                             unsigned int* __restrict__ bins) {
    __shared__ int cur[NBKT];
    for (int i = threadIdx.x; i < NBKT; i += 256) cur[i] = S[i * NB + blockIdx.x];
    __syncthreads();
    int e0 = blockIdx.x * CHUNK;
    for (int e = e0 + threadIdx.x; e < e0 + CHUNK; e += 256) {
        int dd = dst[e];
        int pos = atomicAdd(&cur[dd >> 9], 1);
        bins[pos] = ((unsigned)src[e] << 9) | (unsigned)(dd & 511);
    }
}

// ---- per-bucket: LDS slurp -> degree hist -> block scan -> row[] + in-place CSR ----
__global__ __launch_bounds__(256) void k_build(const int* __restrict__ S,
                                               unsigned int* __restrict__ bins,
                                               int* __restrict__ row) {
    __shared__ unsigned int ebuf[BUF_CAP];   // 96 KB
    __shared__ int hist[512];
    __shared__ int curs[512];
    __shared__ int lds[256];
    int k = blockIdx.x, t = threadIdx.x;
    int e0 = S[k * NB];
    int e1 = (k == NBKT - 1) ? N_EDGES : S[(k + 1) * NB];
    int cnt = min(e1 - e0, BUF_CAP);
    hist[t] = 0; hist[t + 256] = 0;
    __syncthreads();
    for (int i = t; i < cnt; i += 256) {
        unsigned p = bins[e0 + i];
        ebuf[i] = p;
        atomicAdd(&hist[p & 511u], 1);
    }
    __syncthreads();
    int h0 = hist[2 * t], h1 = hist[2 * t + 1];
    lds[t] = h0 + h1;
    __syncthreads();
    for (int off = 1; off < 256; off <<= 1) {
        int cur = lds[t];
        int add = (t >= off) ? lds[t - off] : 0;
        __syncthreads();
        lds[t] = cur + add;
        __syncthreads();
    }
    int run = e0 + lds[t] - (h0 + h1);   // exclusive start for local node 2t
    curs[2 * t] = run;
    curs[2 * t + 1] = run + h0;
    int n0 = k * 512 + 2 * t;
    if (n0 < N_NODES) row[n0] = run;
    if (n0 + 1 < N_NODES) row[n0 + 1] = run + h0;
    if (k == NBKT - 1 && t == 255) row[N_NODES] = N_EDGES;
    __syncthreads();
    for (int i = t; i < cnt; i += 256) {
        unsigned p = ebuf[i];
        int pos = atomicAdd(&curs[p & 511u], 1);
        bins[pos] = p >> 9;              // in-place: now exact CSR (src ids)
    }
}

// ---- layer 1 aggregate: THREAD per node, serial gather, 4-deep ILP ----
__global__ __launch_bounds__(256) void k_agg1(
    const int* __restrict__ row, const unsigned int* __restrict__ csr,
    const float* __restrict__ x, float* __restrict__ agg1) {
    int n = blockIdx.x * 256 + threadIdx.x;
    if (n >= N_NODES) return;
    int r0 = row[n], r1 = row[n + 1];
    float s = 0.0f;
    int j = r0;
    for (; j + 4 <= r1; j += 4) {
        int a0 = (int)csr[j + 0];
        int a1 = (int)csr[j + 1];
        int a2 = (int)csr[j + 2];
        int a3 = (int)csr[j + 3];
        float v0 = x[a0], v1 = x[a1], v2 = x[a2], v3 = x[a3];
        s += (v0 + v1) + (v2 + v3);
    }
    for (; j < r1; ++j) s += x[csr[j]];
    agg1[n] = s / fmaxf((float)(r1 - r0), 1.0f);   // pre-divided mean
}

// ---- layer 1 node update: pure elementwise -> h1b (bf16) ----
__global__ __launch_bounds__(256) void k_h1(
    const float* __restrict__ agg1, const float* __restrict__ x,
    const float* __restrict__ W1l, const float* __restrict__ b1,
    const float* __restrict__ W1r, unsigned short* __restrict__ h1b) {
    int i = blockIdx.x * 256 + threadIdx.x;   // grid covers N_NODES*64 exactly
    int n = i >> 6, f = i & 63;
    float v = agg1[n] * W1l[f] + b1[f] + x[n] * W1r[f];
    h1b[i] = f2bf(fmaxf(v, 0.0f));
}

// ---- layer 2 gather: wave per node, register accumulate ----
__global__ __launch_bounds__(256) void k_gather2(
    const int* __restrict__ row, const unsigned int* __restrict__ csr,
    const unsigned short* __restrict__ h1b,
    unsigned short* __restrict__ agg2b) {
    int gw = (blockIdx.x * 256 + threadIdx.x) >> 6;
    int f = threadIdx.x & 63;
    int nw = gridDim.x * 4;
    for (int n = gw; n < N_NODES; n += nw) {
        int r0 = row[n], r1 = row[n + 1];
        float s = 0.0f;
        for (int base = r0; base < r1; base += 64) {
            int idx = base + f;
            int vs = (idx < r1) ? (int)csr[idx] : 0;
            int c = min(64, r1 - base);
            int j = 0;
            for (; j + 8 <= c; j += 8) {
                int a0 = __builtin_amdgcn_readlane(vs, j + 0);
                int a1 = __builtin_amdgcn_readlane(vs, j + 1);
                int a2 = __builtin_amdgcn_readlane(vs, j + 2);
                int a3 = __builtin_amdgcn_readlane(vs, j + 3);
                int a4 = __builtin_amdgcn_readlane(vs, j + 4);
                int a5 = __builtin_amdgcn_readlane(vs, j + 5);
                int a6 = __builtin_amdgcn_readlane(vs, j + 6);
                int a7 = __builtin_amdgcn_readlane(vs, j + 7);
                float v0 = bf2f(h1b[(size_t)a0 * 64 + f]);
                float v1 = bf2f(h1b[(size_t)a1 * 64 + f]);
                float v2 = bf2f(h1b[(size_t)a2 * 64 + f]);
                float v3 = bf2f(h1b[(size_t)a3 * 64 + f]);
                float v4 = bf2f(h1b[(size_t)a4 * 64 + f]);
                float v5 = bf2f(h1b[(size_t)a5 * 64 + f]);
                float v6 = bf2f(h1b[(size_t)a6 * 64 + f]);
                float v7 = bf2f(h1b[(size_t)a7 * 64 + f]);
                s += ((v0 + v1) + (v2 + v3)) + ((v4 + v5) + (v6 + v7));
            }
            for (; j < c; ++j) {
                int aj = __builtin_amdgcn_readlane(vs, j);
                s += bf2f(h1b[(size_t)aj * 64 + f]);
            }
        }
        float m = s / fmaxf((float)(r1 - r0), 1.0f);
        agg2b[(size_t)n * 64 + f] = f2bf(m);
    }
}

// ---- layer 2 GEMV: LDS weights + relu + mean-pool (flush-on-graph-change) ----
__global__ __launch_bounds__(256) void k_gemv(
    const unsigned short* __restrict__ agg2b, const unsigned short* __restrict__ h1b,
    const float* __restrict__ W2l, const float* __restrict__ b2,
    const float* __restrict__ W2r,
    const int* __restrict__ batch, const float* __restrict__ gcnt,
    float* __restrict__ pooled) {
    __shared__ float wl[4096];   // 16 KB
    __shared__ float wr[4096];   // 16 KB
    for (int i = threadIdx.x; i < 4096; i += 256) { wl[i] = W2l[i]; wr[i] = W2r[i]; }
    __syncthreads();
    int f = threadIdx.x & 63;
    int wid = threadIdx.x >> 6;
    float bias = b2[f];
    int n0 = blockIdx.x * 64 + wid * 16;
    int prevb = -1;
    float accsum = 0.0f;
    for (int t = 0; t < 16; t++) {
        int n = n0 + t;
        if (n >= N_NODES) break;
        float m = bf2f(agg2b[(size_t)n * 64 + f]);
        float h = bf2f(h1b[(size_t)n * 64 + f]);
        float acc = bias;
#pragma unroll
        for (int kk = 0; kk < 64; kk++) {
            acc += rlanef(m, kk) * wl[kk * 64 + f];
            acc += rlanef(h, kk) * wr[kk * 64 + f];
        }
        acc = fmaxf(acc, 0.0f);
        int b = batch[n];
        float scaled = acc / fmaxf(gcnt[b], 1.0f);
        if (b != prevb) {
            if (prevb >= 0) atomicAdd(&pooled[prevb * 64 + f], accsum);
            prevb = b;
            accsum = scaled;
        } else {
            accsum += scaled;
        }
    }
    if (prevb >= 0) atomicAdd(&pooled[prevb * 64 + f], accsum);
}

// ---- classifier ----
__global__ void k_cls(const float* __restrict__ pooled, const float* __restrict__ Wc,
                      const float* __restrict__ bc, float* __restrict__ out) {
    __shared__ float rowv[64];
    int g = blockIdx.x;
    int f = threadIdx.x;
    rowv[f] = pooled[g * 64 + f];
    __syncthreads();
    if (f < NCLS) {
        float acc = bc[f];
#pragma unroll
        for (int kk = 0; kk < 64; kk++) acc += rowv[kk] * Wc[kk * NCLS + f];
        out[g * NCLS + f] = acc;
    }
}

extern "C" void kernel_launch(void* const* d_in, const int* in_sizes, int n_in,
                              void* d_out, int out_size, void* d_ws, size_t ws_size,
                              hipStream_t stream) {
    const float* x     = (const float*)d_in[0];
    const int*   eidx  = (const int*)d_in[1];
    const int*   batch = (const int*)d_in[2];
    const float* W1l   = (const float*)d_in[3];
    const float* b1    = (const float*)d_in[4];
    const float* W1r   = (const float*)d_in[5];
    const float* W2l   = (const float*)d_in[6];
    const float* b2    = (const float*)d_in[7];
    const float* W2r   = (const float*)d_in[8];
    const float* Wc    = (const float*)d_in[9];
    const float* bc    = (const float*)d_in[10];
    float* out = (float*)d_out;

    const int* src = eidx;
    const int* dst = eidx + N_EDGES;

    // workspace ≈ 39.5 MB (proven-safe envelope 40.27 MB)
    char* p = (char*)d_ws;
    unsigned int* bins    = (unsigned int*)p;   p += (size_t)N_EDGES * 4;        // 12.8 MB
    unsigned short* h1b   = (unsigned short*)p; p += (size_t)N_NODES * 64 * 2;   // 12.8 MB
    unsigned short* agg2b = (unsigned short*)p; p += (size_t)N_NODES * 64 * 2;   // 12.8 MB
    int* gh    = (int*)p;                       p += (size_t)SCAN_N * 4;         // 0.2 MB
    int* bsum  = (int*)p;                       p += 64 * 4;
    int* row   = (int*)p;                       p += (size_t)(N_NODES + 1) * 4;  // 0.4 MB
    float* agg1= (float*)p;                     p += (size_t)N_NODES * 4;        // 0.4 MB
    float* gcnt= (float*)p;                     p += N_GRAPHS * 4;
    // ---- zeroed region ----
    float* pooled = (float*)p;                  p += (size_t)N_GRAPHS * 64 * 4;
    size_t zero_bytes = (size_t)(N_GRAPHS * 64) * 4;

    hipMemsetAsync(pooled, 0, zero_bytes, stream);

    k_gcnt <<<(N_GRAPHS + 255) / 256, 256, 0, stream>>>(batch, gcnt);
    k_hist <<<NB, 256, 0, stream>>>(dst, gh);
    k_scan1<<<SCAN_NB1, 256, 0, stream>>>(gh, bsum);
    k_scan2<<<1, 64, 0, stream>>>(bsum);
    k_scan3<<<(SCAN_N + 255) / 256, 256, 0, stream>>>(gh, bsum);
    k_bin  <<<NB, 256, 0, stream>>>(src, dst, gh, bins);
    k_build<<<NBKT, 256, 0, stream>>>(gh, bins, row);

    k_agg1   <<<(N_NODES + 255) / 256, 256, 0, stream>>>(row, bins, x, agg1);
    k_h1     <<<(N_NODES * 64) / 256, 256, 0, stream>>>(agg1, x, W1l, b1, W1r, h1b);
    k_gather2<<<2048, 256, 0, stream>>>(row, bins, h1b, agg2b);
    k_gemv   <<<(N_NODES + 63) / 64, 256, 0, stream>>>(agg2b, h1b, W2l, b2, W2r,
                                                       batch, gcnt, pooled);
    k_cls    <<<N_GRAPHS, 64, 0, stream>>>(pooled, Wc, bc, out);
}